// Round 17
// baseline (12.884 us; speedup 1.0000x reference)
//
#include <hip/hip_runtime.h>
#include <hip/hip_bf16.h>
#include <hip/hip_fp16.h>

// Problem: B=16, N=256, F=64, H=64
// out[b,i,j] = (i==j) ? 1 : sigmoid( sum_h relu(a[b,i,h]+c[b,j,h]) * w2[h] + b2 )
// a = hs @ w1[:, :64]^T + b1, c = hs @ w1[:, 64:]^T
//
// Round-17: 32x32 tiles, 1024 blocks x 256 thr = 16 waves/CU = 4 waves/SIMD,
// 4 independent blocks/CU (28 KB LDS each) so barriers/staging of one block
// overlap compute of the others. Phase-1 MFMA (r14-verified fragments),
// phase-2 f16 pair (r12-verified math), 4 outputs/thread.

#define Nn 256
#define Fd 64
#define Hd 64

typedef _Float16 h2v    __attribute__((ext_vector_type(2)));
typedef __fp16   fp16x2 __attribute__((ext_vector_type(2)));
typedef _Float16 f16x8  __attribute__((ext_vector_type(8)));
typedef float    f32x4  __attribute__((ext_vector_type(4)));
union H2   { h2v v; fp16x2 p; unsigned int u; };
union U4F8 { uint4 u; f16x8 v; };
union HS1  { _Float16 h; unsigned short s; };

__global__ __launch_bounds__(256) void fused_kernel(
    const float* __restrict__ hs, const float* __restrict__ w1,
    const float* __restrict__ b1, const float* __restrict__ w2,
    const float* __restrict__ b2, float* __restrict__ out) {
  __shared__ uint2 w1s[64][32];   // 16 KB: w1 f16, row h, chunk c at c^(h&15)
  __shared__ uint2 hsI[32][16];   //  4 KB: hs i-rows f16, chunk c at c^(r&7)
  __shared__ uint2 hsJ[32][16];   //  4 KB: hs j-rows f16
  __shared__ uint4 aT[32][8];     //  2 KB: a-tile f16 (pair layout)
  __shared__ uint4 cT[32][8];     //  2 KB: c-tile f16
  __shared__ unsigned int w2h[32];

  const int t  = threadIdx.x;
  const int b  = blockIdx.z;
  const int i0 = blockIdx.y * 32;
  const int j0 = blockIdx.x * 32;

  // ---- stage w1 (64x128 f32 -> f16 LDS), coalesced ----
  {
    const float4* w14 = (const float4*)w1;
#pragma unroll
    for (int p = 0; p < 8; ++p) {
      const int k4 = p * 256 + t;            // 0..2047
      const int r = k4 >> 5, col4 = k4 & 31;
      const float4 v = w14[k4];
      H2 lo, hi;
      lo.p = __builtin_amdgcn_cvt_pkrtz(v.x, v.y);
      hi.p = __builtin_amdgcn_cvt_pkrtz(v.z, v.w);
      const int cc = col4 >> 1, hf = col4 & 1;
      w1s[r][((cc ^ (r & 15)) << 1) | hf] = make_uint2(lo.u, hi.u);
    }
  }
  // ---- stage hs i-rows and j-rows (32x64 f32 -> f16 each), coalesced ----
  {
    const float4* hi4 = (const float4*)(hs + (size_t)(b * Nn + i0) * Fd);
    const float4* hj4 = (const float4*)(hs + (size_t)(b * Nn + j0) * Fd);
#pragma unroll
    for (int p = 0; p < 2; ++p) {
      const int k4 = p * 256 + t;            // 0..511
      const int r = k4 >> 4, col4 = k4 & 15;
      const int cc = col4 >> 1, hf = col4 & 1;
      const int idx = ((cc ^ (r & 7)) << 1) | hf;
      {
        const float4 v = hi4[k4];
        H2 lo, hi_;
        lo.p  = __builtin_amdgcn_cvt_pkrtz(v.x, v.y);
        hi_.p = __builtin_amdgcn_cvt_pkrtz(v.z, v.w);
        hsI[r][idx] = make_uint2(lo.u, hi_.u);
      }
      {
        const float4 v = hj4[k4];
        H2 lo, hi_;
        lo.p  = __builtin_amdgcn_cvt_pkrtz(v.x, v.y);
        hi_.p = __builtin_amdgcn_cvt_pkrtz(v.z, v.w);
        hsJ[r][idx] = make_uint2(lo.u, hi_.u);
      }
    }
  }
  if (t < 32) {
    H2 wv2;
    wv2.v = (h2v){(_Float16)w2[2 * t], (_Float16)w2[2 * t + 1]};
    w2h[t] = wv2.u;
  }
  __syncthreads();

  // ---- phase 1: MFMA. waves 0-1 -> a-tile (16 rows each); waves 2-3 -> c ----
  {
    const int l   = t & 63;
    const int w   = t >> 6;                  // 0..3
    const bool isA = (w < 2);
    const int wv  = w & 1;
    const int l15 = l & 15, l4 = l >> 4;
    const int mrow = wv * 16 + l15;          // A-frag row (0..31)

    const uint2 (*hsX)[16] = isA ? hsI : hsJ;
    const int cbase = isA ? 0 : 8;           // w1 chunk base: a cols [0,64), c [64,128)

    f32x4 acc1[4] = {{0,0,0,0},{0,0,0,0},{0,0,0,0},{0,0,0,0}};

#pragma unroll
    for (int s = 0; s < 2; ++s) {
      U4F8 af;
      af.u = ((const uint4*)&hsX[mrow][0])[(s * 4 + l4) ^ (mrow & 7)];
#pragma unroll
      for (int nt = 0; nt < 4; ++nt) {
        const int rh = nt * 16 + l15;        // w1 row = output h
        U4F8 bf;
        bf.u = ((const uint4*)&w1s[rh][0])[(cbase + s * 4 + l4) ^ (rh & 15)];
        acc1[nt] = __builtin_amdgcn_mfma_f32_16x16x32_f16(af.v, bf.v, acc1[nt], 0, 0, 0);
      }
    }

    // epilogue: write tile (f16) into pair-layout LDS
    unsigned short* dTh = isA ? (unsigned short*)aT : (unsigned short*)cT;
#pragma unroll
    for (int nt = 0; nt < 4; ++nt) {
      const int n = nt * 16 + l15;           // h col 0..63
      const float bval = isA ? b1[n] : 0.f;
      const int chunk = n >> 3, pos = n & 7;
#pragma unroll
      for (int i = 0; i < 4; ++i) {
        const int row = wv * 16 + l4 * 4 + i;  // C/D: row=(lane>>4)*4+reg (verified r14)
        const int sw = chunk ^ ((row >> 2) & 7);
        HS1 x; x.h = (_Float16)(acc1[nt][i] + bval);
        dTh[row * 64 + sw * 8 + pos] = x.s;
      }
    }
  }
  __syncthreads();

  // ---- phase 2: pair, 1x4 outputs/thread ----
  const int jt = t & 7;          // j-quad 0..7
  const int it = t >> 3;         // i row 0..31
  const int jb = jt * 4;
  const int sa = (it >> 2) & 7;
  const int sc = jt;

  const uint4* w2q = (const uint4*)w2h;

  float acc[4] = {0.f, 0.f, 0.f, 0.f};

#pragma unroll 2
  for (int h8 = 0; h8 < 8; ++h8) {
    const uint4 wwu = w2q[h8];
    const uint4 av = aT[it][h8 ^ sa];
    uint4 cv[4];
#pragma unroll
    for (int v = 0; v < 4; ++v) cv[v] = cT[jb + v][h8 ^ sc];

    const unsigned au4[4] = {av.x, av.y, av.z, av.w};
    const unsigned wu4[4] = {wwu.x, wwu.y, wwu.z, wwu.w};
#pragma unroll
    for (int v = 0; v < 4; ++v) {
      const unsigned cu4[4] = {cv[v].x, cv[v].y, cv[v].z, cv[v].w};
#pragma unroll
      for (int m = 0; m < 4; ++m) {
        H2 za, zc, zw;
        za.u = au4[m]; zc.u = cu4[m]; zw.u = wu4[m];
        h2v z = __builtin_elementwise_max(za.v + zc.v, (h2v)(_Float16)0);
#if __has_builtin(__builtin_amdgcn_fdot2)
        acc[v] = __builtin_amdgcn_fdot2(z, zw.v, acc[v], false);
#else
        acc[v] = fmaf((float)z.x, (float)zw.v.x, acc[v]);
        acc[v] = fmaf((float)z.y, (float)zw.v.y, acc[v]);
#endif
      }
    }
  }

  const float bias2 = b2[0];
  {
    const int i = i0 + it;
    float4 o;
    o.x = (i == j0 + jb + 0) ? 1.0f : 1.f / (1.f + __expf(-(acc[0] + bias2)));
    o.y = (i == j0 + jb + 1) ? 1.0f : 1.f / (1.f + __expf(-(acc[1] + bias2)));
    o.z = (i == j0 + jb + 2) ? 1.0f : 1.f / (1.f + __expf(-(acc[2] + bias2)));
    o.w = (i == j0 + jb + 3) ? 1.0f : 1.f / (1.f + __expf(-(acc[3] + bias2)));
    ((float4*)(out + (size_t)(b * Nn + i) * Nn + j0))[jt] = o;
  }
}

extern "C" void kernel_launch(void* const* d_in, const int* in_sizes, int n_in,
                              void* d_out, int out_size, void* d_ws, size_t ws_size,
                              hipStream_t stream) {
  const float* hs = (const float*)d_in[0];
  const float* w1 = (const float*)d_in[1];
  const float* b1 = (const float*)d_in[2];
  const float* w2 = (const float*)d_in[3];
  const float* b2 = (const float*)d_in[4];
  float* out = (float*)d_out;

  dim3 grid(Nn / 32, Nn / 32, 16);   // (j-tiles, i-tiles, b) = 1024 blocks
  fused_kernel<<<grid, 256, 0, stream>>>(hs, w1, b1, w2, b2, out);
}

// Round 18
// 12.164 us; speedup vs baseline: 1.0592x; 1.0592x over previous
//
#include <hip/hip_runtime.h>
#include <hip/hip_bf16.h>
#include <hip/hip_fp16.h>

// Problem: B=16, N=256, F=64, H=64
// out[b,i,j] = (i==j) ? 1 : sigmoid( sum_h relu(a[b,i,h]+c[b,j,h]) * w2[h] + b2 )
// a = hs @ w1[:, :64]^T + b1, c = hs @ w1[:, 64:]^T
//
// Round-18: r16 (best, 12.06us) + wave-staggered phase-2: wave w starts its
// h8 loop at offset w, so the 8 waves' ds_read/lgkm-wait points interleave
// instead of stalling in lockstep after the barrier (r5 signature:
// VALUBusy 26% with zero memory traffic in the hot loop).

#define Nn 256
#define Fd 64
#define Hd 64

typedef _Float16 h2v    __attribute__((ext_vector_type(2)));
typedef __fp16   fp16x2 __attribute__((ext_vector_type(2)));
typedef _Float16 f16x8  __attribute__((ext_vector_type(8)));
typedef float    f32x4  __attribute__((ext_vector_type(4)));
union H2   { h2v v; fp16x2 p; unsigned int u; };
union U4F8 { uint4 u; f16x8 v; };
union HS1  { _Float16 h; unsigned short s; };

__global__ __launch_bounds__(512) void fused_kernel(
    const float* __restrict__ hs, const float* __restrict__ w1,
    const float* __restrict__ b1, const float* __restrict__ w2,
    const float* __restrict__ b2, float* __restrict__ out) {
  __shared__ uint2 w1s[64][32];   // 16 KB: w1 f16, row h, chunk c at c^(h&15)
  __shared__ uint2 hsI[64][16];   //  8 KB: hs i-rows f16, chunk c at c^(r&7)
  __shared__ uint2 hsJ[64][16];   //  8 KB: hs j-rows f16
  __shared__ uint4 aT[64][8];     //  4 KB: a-tile f16 (pair layout)
  __shared__ uint4 cT[64][8];     //  4 KB: c-tile f16
  __shared__ unsigned int w2h[32];

  const int t  = threadIdx.x;
  const int b  = blockIdx.z;
  const int i0 = blockIdx.y * 64;
  const int j0 = blockIdx.x * 64;

  // ---- stage w1 (64x128 f32 -> f16 LDS), coalesced ----
  {
    const float4* w14 = (const float4*)w1;
#pragma unroll
    for (int p = 0; p < 4; ++p) {
      const int k4 = p * 512 + t;            // 0..2047
      const int r = k4 >> 5, col4 = k4 & 31;
      const float4 v = w14[k4];
      H2 lo, hi;
      lo.p = __builtin_amdgcn_cvt_pkrtz(v.x, v.y);
      hi.p = __builtin_amdgcn_cvt_pkrtz(v.z, v.w);
      const int cc = col4 >> 1, hf = col4 & 1;
      w1s[r][((cc ^ (r & 15)) << 1) | hf] = make_uint2(lo.u, hi.u);
    }
  }
  // ---- stage hs i-rows and j-rows (64x64 f32 -> f16), coalesced ----
  {
    const float4* hi4 = (const float4*)(hs + (size_t)(b * Nn + i0) * Fd);
    const float4* hj4 = (const float4*)(hs + (size_t)(b * Nn + j0) * Fd);
#pragma unroll
    for (int p = 0; p < 2; ++p) {
      const int k4 = p * 512 + t;            // 0..1023
      const int r = k4 >> 4, col4 = k4 & 15;
      const int cc = col4 >> 1, hf = col4 & 1;
      const int idx = ((cc ^ (r & 7)) << 1) | hf;
      {
        const float4 v = hi4[k4];
        H2 lo, hi_;
        lo.p  = __builtin_amdgcn_cvt_pkrtz(v.x, v.y);
        hi_.p = __builtin_amdgcn_cvt_pkrtz(v.z, v.w);
        hsI[r][idx] = make_uint2(lo.u, hi_.u);
      }
      {
        const float4 v = hj4[k4];
        H2 lo, hi_;
        lo.p  = __builtin_amdgcn_cvt_pkrtz(v.x, v.y);
        hi_.p = __builtin_amdgcn_cvt_pkrtz(v.z, v.w);
        hsJ[r][idx] = make_uint2(lo.u, hi_.u);
      }
    }
  }
  if (t < 32) {
    H2 wv2;
    wv2.v = (h2v){(_Float16)w2[2 * t], (_Float16)w2[2 * t + 1]};
    w2h[t] = wv2.u;
  }
  __syncthreads();

  // ---- phase 1: MFMA. waves 0-3 -> a-tile rows 16w..; waves 4-7 -> c-tile ----
  {
    const int l   = t & 63;
    const int w   = t >> 6;                  // 0..7
    const bool isA = (w < 4);
    const int wv  = w & 3;
    const int l15 = l & 15, l4 = l >> 4;
    const int mrow = wv * 16 + l15;          // A-frag row

    const uint2 (*hsX)[16] = isA ? hsI : hsJ;
    const int cbase = isA ? 0 : 8;           // w1 chunk base: a cols [0,64), c [64,128)

    f32x4 acc1[4] = {{0,0,0,0},{0,0,0,0},{0,0,0,0},{0,0,0,0}};

#pragma unroll
    for (int s = 0; s < 2; ++s) {
      U4F8 af;
      af.u = ((const uint4*)&hsX[mrow][0])[(s * 4 + l4) ^ (mrow & 7)];
#pragma unroll
      for (int nt = 0; nt < 4; ++nt) {
        const int rh = nt * 16 + l15;        // w1 row = output h
        U4F8 bf;
        bf.u = ((const uint4*)&w1s[rh][0])[(cbase + s * 4 + l4) ^ (rh & 15)];
        acc1[nt] = __builtin_amdgcn_mfma_f32_16x16x32_f16(af.v, bf.v, acc1[nt], 0, 0, 0);
      }
    }

    // epilogue: write tile (f16) into pair-layout LDS
    unsigned short* dTh = isA ? (unsigned short*)aT : (unsigned short*)cT;
#pragma unroll
    for (int nt = 0; nt < 4; ++nt) {
      const int n = nt * 16 + l15;           // h col 0..63
      const float bval = isA ? b1[n] : 0.f;
      const int chunk = n >> 3, pos = n & 7;
#pragma unroll
      for (int i = 0; i < 4; ++i) {
        const int row = wv * 16 + l4 * 4 + i;  // C/D: row=(lane>>4)*4+reg (verified r14)
        const int sw = chunk ^ ((row >> 2) & 7);
        HS1 x; x.h = (_Float16)(acc1[nt][i] + bval);
        dTh[row * 64 + sw * 8 + pos] = x.s;
      }
    }
  }
  __syncthreads();

  // ---- phase 2: pair (2x4 outputs/thread), wave-staggered h8 order ----
  const int jt  = t & 15;
  const int it2 = t >> 4;        // 0..31
  const int ib  = it2 * 2;
  const int jb  = jt * 4;
  const int sa  = (it2 >> 1) & 7;   // ((ib+u)>>2)&7, uniform for u=0,1
  const int sc  = jt & 7;
  const int h0  = t >> 6;           // wave 0..7: stagger offset

  const uint4* w2q = (const uint4*)w2h;

  float acc[2][4] = {{0.f}};

#pragma unroll 2
  for (int k = 0; k < 8; ++k) {
    const int h8 = (k + h0) & 7;
    const uint4 wwu = w2q[h8];
    uint4 av[2], cv[4];
#pragma unroll
    for (int u = 0; u < 2; ++u) av[u] = aT[ib + u][h8 ^ sa];
#pragma unroll
    for (int v = 0; v < 4; ++v) cv[v] = cT[jb + v][h8 ^ sc];

#pragma unroll
    for (int u = 0; u < 2; ++u) {
      const unsigned au4[4] = {av[u].x, av[u].y, av[u].z, av[u].w};
#pragma unroll
      for (int v = 0; v < 4; ++v) {
        const unsigned cu4[4] = {cv[v].x, cv[v].y, cv[v].z, cv[v].w};
        const unsigned wu4[4] = {wwu.x, wwu.y, wwu.z, wwu.w};
#pragma unroll
        for (int m = 0; m < 4; ++m) {
          H2 za, zc, zw;
          za.u = au4[m]; zc.u = cu4[m]; zw.u = wu4[m];
          h2v z = __builtin_elementwise_max(za.v + zc.v, (h2v)(_Float16)0);
#if __has_builtin(__builtin_amdgcn_fdot2)
          acc[u][v] = __builtin_amdgcn_fdot2(z, zw.v, acc[u][v], false);
#else
          acc[u][v] = fmaf((float)z.x, (float)zw.v.x, acc[u][v]);
          acc[u][v] = fmaf((float)z.y, (float)zw.v.y, acc[u][v]);
#endif
        }
      }
    }
  }

  const float bias2 = b2[0];
#pragma unroll
  for (int u = 0; u < 2; ++u) {
    const int i = i0 + ib + u;
    float4 o;
    o.x = (i == j0 + jb + 0) ? 1.0f : 1.f / (1.f + __expf(-(acc[u][0] + bias2)));
    o.y = (i == j0 + jb + 1) ? 1.0f : 1.f / (1.f + __expf(-(acc[u][1] + bias2)));
    o.z = (i == j0 + jb + 2) ? 1.0f : 1.f / (1.f + __expf(-(acc[u][2] + bias2)));
    o.w = (i == j0 + jb + 3) ? 1.0f : 1.f / (1.f + __expf(-(acc[u][3] + bias2)));
    ((float4*)(out + (size_t)(b * Nn + i) * Nn + j0))[jt] = o;
  }
}

extern "C" void kernel_launch(void* const* d_in, const int* in_sizes, int n_in,
                              void* d_out, int out_size, void* d_ws, size_t ws_size,
                              hipStream_t stream) {
  const float* hs = (const float*)d_in[0];
  const float* w1 = (const float*)d_in[1];
  const float* b1 = (const float*)d_in[2];
  const float* w2 = (const float*)d_in[3];
  const float* b2 = (const float*)d_in[4];
  float* out = (float*)d_out;

  dim3 grid(Nn / 64, Nn / 64, 16);   // (j-tiles, i-tiles, b) = 256 blocks
  fused_kernel<<<grid, 512, 0, stream>>>(hs, w1, b1, w2, b2, out);
}